// Round 6
// baseline (292.320 us; speedup 1.0000x reference)
//
#include <hip/hip_runtime.h>
#include <hip/hip_bf16.h>

#define NB 32
#define TS 300
#define NBATCH 16384
#define DTF (1.0f/300.0f)
#define A_ELEMS (NBATCH*2*TS)   /* 9,830,400 */

typedef __attribute__((ext_vector_type(8))) short bf16x8;
typedef __attribute__((ext_vector_type(4))) float f32x4;

static __device__ __forceinline__ ushort f2bf(float f) {
    union { __hip_bfloat16 h; ushort u; } cv;
    cv.h = __float2bfloat16(f);
    return cv.u;
}
static __device__ __forceinline__ float rdlane(float v, int lane) {
    return __int_as_float(__builtin_amdgcn_readlane(__float_as_int(v), lane));
}

// ============ PROBE 1: linear full-line stores, 5x real a+v volume ============
__global__ __launch_bounds__(256) void p1_lin(float* __restrict__ a_out,
                                              float* __restrict__ v_out) {
    const int tid = blockIdx.x * 256 + threadIdx.x;
    #pragma unroll 1
    for (int rep = 0; rep < 5; ++rep) {
        const float4 val = make_float4((float)rep, (float)tid, 1.0f, 2.0f);
        #pragma unroll 1
        for (int i = tid; i < 2457600; i += 131072) {
            ((float4*)a_out)[i] = val;
            ((float4*)v_out)[i] = val;
        }
    }
}

// ============ PROBE 2: R4's exact scattered-quad pattern, 5x volume ============
__global__ __launch_bounds__(256) void p2_scat(float* __restrict__ a_out,
                                               float* __restrict__ v_out) {
    const int tid = threadIdx.x;
    const int wv = tid >> 6, j = tid & 63;
    const int m_st = blockIdx.x * 64 + wv * 16 + (j >> 2);
    float* aptr = a_out + m_st * TS + (j & 3) * 4;
    float* vptr = v_out + m_st * TS + (j & 3) * 4;
    const bool tail_ok = (j & 3) < 3;
    #pragma unroll 1
    for (int rep = 0; rep < 5; ++rep) {
        const float4 val = make_float4((float)rep, (float)tid, 3.0f, 4.0f);
        #pragma unroll 1
        for (int c = 0; c < 19; ++c) {
            if (c < 18 || tail_ok) {
                *(float4*)(aptr + c * 16) = val;
                *(float4*)(vptr + c * 16) = val;
            }
        }
    }
}

// ============ PROBE 3: rollout compute only (no stores), 20x ============
__global__ __launch_bounds__(256) void p3_comp(const float* __restrict__ dmp_c,
                                               const float* __restrict__ dmp_s2,
                                               float* __restrict__ ws) {
    __shared__ ushort phis[304*NB];
    const int tid = threadIdx.x;
    {
        const float l2 = log2f(1.0f - DTF);
        for (int t = tid; t < 304; t += 256) {
            ushort row[NB];
            if (t < TS) {
                const float x = exp2f((float)(t + 1) * l2);
                float ps[NB]; float s = 0.0f;
                #pragma unroll
                for (int n = 0; n < NB; ++n) {
                    float d = x - dmp_c[n];
                    float p = __expf(-0.5f * d * d / dmp_s2[n]);
                    ps[n] = p; s += p;
                }
                const float inv = x / s;
                #pragma unroll
                for (int n = 0; n < NB; ++n) row[n] = f2bf(ps[n] * inv);
            } else {
                #pragma unroll
                for (int n = 0; n < NB; ++n) row[n] = 0;
            }
            uint4* dst = (uint4*)(phis + t*NB);
            #pragma unroll
            for (int q4 = 0; q4 < 4; ++q4) {
                union { ushort us[8]; uint4 v; } pk;
                #pragma unroll
                for (int e = 0; e < 8; ++e) pk.us[e] = row[q4*8 + e];
                dst[q4 ^ (t & 3)] = pk.v;
            }
        }
    }
    __syncthreads();

    const int j  = tid & 63;
    const int ch = j & 15;
    const int g  = j >> 4;
    bf16x8 wb;
    {
        union { bf16x8 v; ushort u[8]; } uw;
        #pragma unroll
        for (int e = 0; e < 8; ++e) uw.u[e] = f2bf(0.01f * (float)(j + e + 1));
        wb = uw.v;
    }
    const ushort* aprow = phis + ch*NB + ((g ^ (ch & 3)) << 3);
    const float Ac = DTF * 2.0f, Bc = DTF * 3.0f, Kc = DTF * 0.5f, c0 = Ac * 0.7f;
    float y = 0.5f + 0.001f * (float)blockIdx.x;
    float z = 0.01f;
    const f32x4 zacc = {0.0f, 0.0f, 0.0f, 0.0f};

    #pragma unroll 1
    for (int rep = 0; rep < 20; ++rep) {
        bf16x8 af = *(const bf16x8*)aprow;
        #pragma unroll 1
        for (int c = 0; c < 19; ++c) {
            f32x4 facc = __builtin_amdgcn_mfma_f32_16x16x32_bf16(af, wb, zacc, 0, 0, 0);
            if (c < 18) af = *(const bf16x8*)(aprow + (c + 1)*16*NB);
            float F[16];
            #pragma unroll
            for (int q = 0; q < 4; ++q) {
                float a = facc[q], b = facc[q];
                asm volatile("v_permlane16_swap_b32 %0, %1" : "+v"(a), "+v"(b));
                float a2 = a, b2 = b;
                asm volatile("v_permlane32_swap_b32 %0, %1" : "+v"(a), "+v"(a2));
                asm volatile("v_permlane32_swap_b32 %0, %1" : "+v"(b), "+v"(b2));
                F[0*4+q] = a; F[1*4+q] = b; F[2*4+q] = a2; F[3*4+q] = b2;
            }
            #pragma unroll
            for (int i = 0; i < 16; ++i) {
                const float aval = z * DTF;
                float u = z + c0;
                u = fmaf(Kc, F[i], u);
                u = fmaf(-Bc, z, u);
                z = fmaf(-Ac, y, u);
                y += aval;
            }
        }
    }
    ws[blockIdx.x * 256 + tid] = z + y;   // keep live
}

// ============ REAL KERNEL: exact R4 (34 us best known) ============
__global__ __launch_bounds__(256) void k_fused(
    const float* __restrict__ state,
    const float* __restrict__ fc1_w, const float* __restrict__ fc1_b,
    const float* __restrict__ fc2m_w, const float* __restrict__ fc2m_b,
    const float* __restrict__ sig_w, const float* __restrict__ sig_b,
    const float* __restrict__ val_w, const float* __restrict__ val_b,
    const float* __restrict__ dmp_c, const float* __restrict__ dmp_s2,
    float* __restrict__ sig_out, float* __restrict__ a_out,
    float* __restrict__ v_out)
{
    __shared__ ushort phis[304*NB];
    __shared__ float  wlds[70*64];
    __shared__ float  f1[64*4];
    __shared__ ushort wloc[64*NB];
    __shared__ float4 ppl[64];
    __shared__ float4 xt[4][16][5];

    const int tid = threadIdx.x;
    const int wv  = tid >> 6;
    const int j   = tid & 63;

    for (int i = tid; i < 70*64; i += 256) {
        const int row = i >> 6, col = i & 63;
        float v;
        if (row < 66)      v = fc2m_w[i];
        else if (row < 68) v = sig_w[(row-66)*64 + col];
        else               v = val_w[(row-68)*64 + col];
        const int q = col >> 2, e = col & 3;
        wlds[row*64 + (((q ^ (row & 15)) << 2) | e)] = v;
    }
    if (tid < 64) {
        f1[tid*4+0] = fc1_w[tid*3+0];
        f1[tid*4+1] = fc1_w[tid*3+1];
        f1[tid*4+2] = fc1_w[tid*3+2];
        f1[tid*4+3] = fc1_b[tid];
    }
    {
        const float l2 = log2f(1.0f - DTF);
        for (int t = tid; t < 304; t += 256) {
            ushort row[NB];
            if (t < TS) {
                const float x = exp2f((float)(t + 1) * l2);
                float ps[NB]; float s = 0.0f;
                #pragma unroll
                for (int n = 0; n < NB; ++n) {
                    float d = x - dmp_c[n];
                    float p = __expf(-0.5f * d * d / dmp_s2[n]);
                    ps[n] = p; s += p;
                }
                const float inv = x / s;
                #pragma unroll
                for (int n = 0; n < NB; ++n) row[n] = f2bf(ps[n] * inv);
            } else {
                #pragma unroll
                for (int n = 0; n < NB; ++n) row[n] = 0;
            }
            uint4* dst = (uint4*)(phis + t*NB);
            #pragma unroll
            for (int q4 = 0; q4 < 4; ++q4) {
                union { ushort us[8]; uint4 v; } pk;
                #pragma unroll
                for (int e = 0; e < 8; ++e) pk.us[e] = row[q4*8 + e];
                dst[q4 ^ (t & 3)] = pk.v;
            }
        }
    }
    __syncthreads();

    {
        const int r2 = 64 + (j % 6);
        float wr[64], w2[64];
        #pragma unroll
        for (int q = 0; q < 16; ++q) {
            float4 a  = *(const float4*)(wlds + j*64  + ((q ^ (j  & 15)) << 2));
            wr[q*4+0]=a.x; wr[q*4+1]=a.y; wr[q*4+2]=a.z; wr[q*4+3]=a.w;
            float4 b4 = *(const float4*)(wlds + r2*64 + ((q ^ (r2 & 15)) << 2));
            w2[q*4+0]=b4.x; w2[q*4+1]=b4.y; w2[q*4+2]=b4.z; w2[q*4+3]=b4.w;
        }
        const float bias1 = fc2m_b[j];
        const float bias2 = (r2 < 66) ? fc2m_b[r2] : (r2 < 68) ? sig_b[r2-66] : val_b[r2-68];
        const float4 fw = *(const float4*)(f1 + j*4);

        const int bbase = (blockIdx.x << 5) + (wv << 3);
        float sreg = (j < 24) ? state[bbase*3 + j] : 0.0f;

        for (int it = 0; it < 8; ++it) {
            const float s0  = rdlane(sreg, it*3+0);
            const float s1  = rdlane(sreg, it*3+1);
            const float s2v = rdlane(sreg, it*3+2);
            float pre = fmaf(fw.x, s0, fmaf(fw.y, s1, fmaf(fw.z, s2v, fw.w)));
            float e = __expf(2.0f * pre);
            float h = (1.0f - 2.0f/(e + 1.0f)) * 0.1f;
            float a1 = bias1, a1b = 0.0f, a2 = bias2, a2b = 0.0f;
            #pragma unroll
            for (int k = 0; k < 64; k += 2) {
                const float h0 = rdlane(h, k);
                const float h1 = rdlane(h, k+1);
                a1  = fmaf(wr[k],   h0, a1 );
                a1b = fmaf(wr[k+1], h1, a1b);
                a2  = fmaf(w2[k],   h0, a2 );
                a2b = fmaf(w2[k+1], h1, a2b);
            }
            a1 += a1b; a2 += a2b;
            float az = rdlane(a2, 1);
            az = fminf(fmaxf(az, 0.5f), 30.0f);
            const float vv0 = rdlane(a2, 4);
            const float vv1 = rdlane(a2, 5);
            const int chp = (wv << 4) + (it << 1);
            if (j >= 2) wloc[(chp + ((j-2) >> 5))*NB + ((j-2) & 31)] = f2bf(a1);
            else        wloc[(chp + 1)*NB + 30 + j]                  = f2bf(a2);
            if (j == 2 || j == 3)
                sig_out[(bbase + it)*2 + j - 2] = 1.0f / (1.0f + __expf(-a2)) + 0.001f;
            if (j < 2) {
                const float y0 = (j == 0) ? s0 : s1;
                const float vvl = (j == 0) ? vv0 : vv1;
                ppl[chp + j] = make_float4(a1, a1 - y0, az, vvl);
            }
        }
    }
    __syncthreads();

    const int ch = j & 15;
    const int g  = j >> 4;
    const int chl = (wv << 4) + ch;

    const float4 pp = ppl[chl];
    const float az = pp.z;
    const float Ac = DTF * az * az * 0.25f;
    const float Bc = DTF * az;
    const float Kc = DTF * pp.y;
    const float c0 = Ac * pp.x;
    float y = pp.x - pp.y;
    float z = 0.01f;

    const bf16x8 wb = *(const bf16x8*)(wloc + chl*NB + g*8);
    const ushort* aprow = phis + ch*NB + ((g ^ (ch & 3)) << 3);
    bf16x8 af = *(const bf16x8*)aprow;

    const int mloc = j >> 2;
    const int m_st = (blockIdx.x << 6) + (wv << 4) + mloc;
    const float fv = ppl[(wv << 4) + mloc].w;
    const float4 vsp = make_float4(fv, fv, fv, fv);
    float* aptr = a_out + m_st*TS + (j & 3)*4;
    float* vptr = v_out + m_st*TS + (j & 3)*4;
    const bool tail_ok = (j & 3) < 3;

    const f32x4 zacc = {0.0f, 0.0f, 0.0f, 0.0f};

    for (int c = 0; c < 19; ++c) {
        f32x4 facc = __builtin_amdgcn_mfma_f32_16x16x32_bf16(af, wb, zacc, 0, 0, 0);
        if (c < 18) af = *(const bf16x8*)(aprow + (c + 1)*16*NB);

        float F[16];
        #pragma unroll
        for (int q = 0; q < 4; ++q) {
            float a = facc[q], b = facc[q];
            asm volatile("v_permlane16_swap_b32 %0, %1" : "+v"(a), "+v"(b));
            float a2 = a, b2 = b;
            asm volatile("v_permlane32_swap_b32 %0, %1" : "+v"(a), "+v"(a2));
            asm volatile("v_permlane32_swap_b32 %0, %1" : "+v"(b), "+v"(b2));
            F[0*4+q] = a; F[1*4+q] = b; F[2*4+q] = a2; F[3*4+q] = b2;
        }

        float avq[4] = {0.f, 0.f, 0.f, 0.f};
        #pragma unroll
        for (int i = 0; i < 16; ++i) {
            const float aval = z * DTF;
            if (g == (i >> 2)) avq[i & 3] = aval;
            float u = z + c0;
            u = fmaf(Kc, F[i], u);
            u = fmaf(-Bc, z, u);
            z = fmaf(-Ac, y, u);
            y += aval;
        }

        xt[wv][ch][g] = make_float4(avq[0], avq[1], avq[2], avq[3]);
        if (c < 18 || tail_ok) {
            const float4 s4 = xt[wv][mloc][j & 3];
            *(float4*)aptr = s4;
            *(float4*)vptr = vsp;
        }
        aptr += 16; vptr += 16;
    }
}

extern "C" void kernel_launch(void* const* d_in, const int* in_sizes, int n_in,
                              void* d_out, int out_size, void* d_ws, size_t ws_size,
                              hipStream_t stream) {
    (void)in_sizes; (void)n_in; (void)out_size; (void)ws_size;
    const float* state  = (const float*)d_in[0];
    const float* fc1_w  = (const float*)d_in[1];
    const float* fc1_b  = (const float*)d_in[2];
    const float* fc2m_w = (const float*)d_in[3];
    const float* fc2m_b = (const float*)d_in[4];
    const float* sig_w  = (const float*)d_in[5];
    const float* sig_b  = (const float*)d_in[6];
    const float* val_w  = (const float*)d_in[7];
    const float* val_b  = (const float*)d_in[8];
    const float* dmp_c  = (const float*)d_in[9];
    const float* dmp_s2 = (const float*)d_in[10];

    float* out     = (float*)d_out;
    float* a_out   = out;
    float* sig_out = out + A_ELEMS;
    float* v_out   = out + A_ELEMS + NBATCH*2;

    // --- diagnostics (overwritten by the real kernel below) ---
    p1_lin <<<dim3(512), dim3(256), 0, stream>>>(a_out, v_out);
    p2_scat<<<dim3(512), dim3(256), 0, stream>>>(a_out, v_out);
    p3_comp<<<dim3(512), dim3(256), 0, stream>>>(dmp_c, dmp_s2, (float*)d_ws);

    // --- real kernel (exact R4) ---
    k_fused<<<dim3(512), dim3(256), 0, stream>>>(state, fc1_w, fc1_b, fc2m_w, fc2m_b,
                                                 sig_w, sig_b, val_w, val_b,
                                                 dmp_c, dmp_s2,
                                                 sig_out, a_out, v_out);
}

// Round 7
// 42.040 us; speedup vs baseline: 6.9534x; 6.9534x over previous
//
#include <hip/hip_runtime.h>
#include <hip/hip_bf16.h>

#define NB 32
#define TS 300
#define NBATCH 16384
#define DTF (1.0f/300.0f)
#define A_ELEMS (NBATCH*2*TS)   /* 9,830,400 */

typedef __attribute__((ext_vector_type(8))) short bf16x8;
typedef __attribute__((ext_vector_type(4))) float f32x4;

static __device__ __forceinline__ ushort f2bf(float f) {
    union { __hip_bfloat16 h; ushort u; } cv;
    cv.h = __float2bfloat16(f);
    return cv.u;
}
static __device__ __forceinline__ float rdlane(float v, int lane) {
    return __int_as_float(__builtin_amdgcn_readlane(__float_as_int(v), lane));
}

// Fused kernel, redundancy-free recurrence (post-R6-probe design).
// Phase 0: weights->LDS (aliased into F-tile region), phi[304][32] bf16 ->LDS.
// Phase 1: heads (rdlane broadcast, no barriers) -> wloc/ppl LDS + sig_out.
// Phase 2a: F-precompute: each wave 19 MFMAs for its 16 channels; facc
//           written as bf16 to F-tile [64ch][78 slots of 4t] (LDS transpose).
// Phase 2b: wave0: 64 recurrences, lane=channel, 1 ds_read_b64 + ~26 VALU +
//           1 global_store_dwordx4 per 4 steps (75 clean quads).
//           waves1-3: v-sweep (linear float4, value constant per row).
__global__ __launch_bounds__(256, 2) void k_fused(
    const float* __restrict__ state,
    const float* __restrict__ fc1_w, const float* __restrict__ fc1_b,
    const float* __restrict__ fc2m_w, const float* __restrict__ fc2m_b,
    const float* __restrict__ sig_w, const float* __restrict__ sig_b,
    const float* __restrict__ val_w, const float* __restrict__ val_b,
    const float* __restrict__ dmp_c, const float* __restrict__ dmp_s2,
    float* __restrict__ sig_out, float* __restrict__ a_out,
    float* __restrict__ v_out)
{
    __shared__ float smemf[16128];            // 64,512 B
    char* smem = (char*)smemf;
    ushort* phis = (ushort*)smem;             // [304*32] bf16   (0..19455)
    ushort* wloc = (ushort*)(smem + 19456);   // [64*32]  bf16   (..23551)
    float*  pplf = (float*)(smem + 23552);    // [64*4]   f32    (..24575)
    char*   ftb  = smem + 24576;              // F-tile 64 x 624 B (..64511)
    float*  wlds = (float*)(smem + 24576);    // alias, dead after heads
    float*  f1   = (float*)(smem + 42496);    // alias, dead after heads

    const int tid = threadIdx.x;
    const int wv  = tid >> 6;
    const int j   = tid & 63;

    // ---- phase 0a: weights -> LDS (quad-XOR swizzled rows) ----
    for (int i = tid; i < 70*64; i += 256) {
        const int row = i >> 6, col = i & 63;
        float v;
        if (row < 66)      v = fc2m_w[i];
        else if (row < 68) v = sig_w[(row-66)*64 + col];
        else               v = val_w[(row-68)*64 + col];
        const int q = col >> 2, e = col & 3;
        wlds[row*64 + (((q ^ (row & 15)) << 2) | e)] = v;
    }
    if (tid < 64) {
        f1[tid*4+0] = fc1_w[tid*3+0];
        f1[tid*4+1] = fc1_w[tid*3+1];
        f1[tid*4+2] = fc1_w[tid*3+2];
        f1[tid*4+3] = fc1_b[tid];
    }
    // ---- phase 0b: phi table bf16, slot^(t&3) swizzle ----
    {
        const float l2 = log2f(1.0f - DTF);
        for (int t = tid; t < 304; t += 256) {
            ushort row[NB];
            if (t < TS) {
                const float x = exp2f((float)(t + 1) * l2);
                float ps[NB]; float s = 0.0f;
                #pragma unroll
                for (int n = 0; n < NB; ++n) {
                    float d = x - dmp_c[n];
                    float p = __expf(-0.5f * d * d / dmp_s2[n]);
                    ps[n] = p; s += p;
                }
                const float inv = x / s;
                #pragma unroll
                for (int n = 0; n < NB; ++n) row[n] = f2bf(ps[n] * inv);
            } else {
                #pragma unroll
                for (int n = 0; n < NB; ++n) row[n] = 0;
            }
            uint4* dst = (uint4*)(phis + t*NB);
            #pragma unroll
            for (int q4 = 0; q4 < 4; ++q4) {
                union { ushort us[8]; uint4 v; } pk;
                #pragma unroll
                for (int e = 0; e < 8; ++e) pk.us[e] = row[q4*8 + e];
                dst[q4 ^ (t & 3)] = pk.v;
            }
        }
    }
    __syncthreads();

    // ---- phase 1: heads (4 waves x 8 batches) ----
    {
        const int r2 = 64 + (j % 6);
        float wr[64], w2[64];
        #pragma unroll
        for (int q = 0; q < 16; ++q) {
            float4 a  = *(const float4*)(wlds + j*64  + ((q ^ (j  & 15)) << 2));
            wr[q*4+0]=a.x; wr[q*4+1]=a.y; wr[q*4+2]=a.z; wr[q*4+3]=a.w;
            float4 b4 = *(const float4*)(wlds + r2*64 + ((q ^ (r2 & 15)) << 2));
            w2[q*4+0]=b4.x; w2[q*4+1]=b4.y; w2[q*4+2]=b4.z; w2[q*4+3]=b4.w;
        }
        const float bias1 = fc2m_b[j];
        const float bias2 = (r2 < 66) ? fc2m_b[r2] : (r2 < 68) ? sig_b[r2-66] : val_b[r2-68];
        const float4 fw = *(const float4*)(f1 + j*4);

        const int bbase = (blockIdx.x << 5) + (wv << 3);
        float sreg = (j < 24) ? state[bbase*3 + j] : 0.0f;

        for (int it = 0; it < 8; ++it) {
            const float s0  = rdlane(sreg, it*3+0);
            const float s1  = rdlane(sreg, it*3+1);
            const float s2v = rdlane(sreg, it*3+2);
            float pre = fmaf(fw.x, s0, fmaf(fw.y, s1, fmaf(fw.z, s2v, fw.w)));
            float e = __expf(2.0f * pre);
            float h = (1.0f - 2.0f/(e + 1.0f)) * 0.1f;   // tanh, overflow-safe
            float a1 = bias1, a1b = 0.0f, a2 = bias2, a2b = 0.0f;
            #pragma unroll
            for (int k = 0; k < 64; k += 2) {
                const float h0 = rdlane(h, k);
                const float h1 = rdlane(h, k+1);
                a1  = fmaf(wr[k],   h0, a1 );
                a1b = fmaf(wr[k+1], h1, a1b);
                a2  = fmaf(w2[k],   h0, a2 );
                a2b = fmaf(w2[k+1], h1, a2b);
            }
            a1 += a1b; a2 += a2b;
            float az = rdlane(a2, 1);                    // raw row 65
            az = fminf(fmaxf(az, 0.5f), 30.0f);
            const float vv0 = rdlane(a2, 4);             // value row 68
            const float vv1 = rdlane(a2, 5);             // value row 69
            const int chp = (wv << 4) + (it << 1);
            if (j >= 2) wloc[(chp + ((j-2) >> 5))*NB + ((j-2) & 31)] = f2bf(a1);
            else        wloc[(chp + 1)*NB + 30 + j]                  = f2bf(a2);
            if (j == 2 || j == 3)
                sig_out[(bbase + it)*2 + j - 2] = 1.0f / (1.0f + __expf(-a2)) + 0.001f;
            if (j < 2) {
                const float y0 = (j == 0) ? s0 : s1;
                const float vvl = (j == 0) ? vv0 : vv1;
                *(float4*)(pplf + (chp + j)*4) = make_float4(a1, a1 - y0, az, vvl);
            }
        }
    }
    __syncthreads();   // wlds/f1 (aliased with F-tile) now dead; wloc/ppl ready

    // ---- phase 2a: F-precompute (each wave: its 16 channels, 19 MFMAs) ----
    {
        const int ch = j & 15, g = j >> 4;
        const int chl = (wv << 4) + ch;
        const bf16x8 wb = *(const bf16x8*)(wloc + chl*NB + g*8);
        const ushort* aprow = phis + ch*NB + ((g ^ (ch & 3)) << 3);
        bf16x8 af = *(const bf16x8*)aprow;
        const f32x4 zacc = {0.0f, 0.0f, 0.0f, 0.0f};
        // lane writes F[t-quad] for its channel: row chl, slot c*4+g
        char* wp = ftb + chl*624 + g*8;
        for (int c = 0; c < 19; ++c) {
            f32x4 facc = __builtin_amdgcn_mfma_f32_16x16x32_bf16(af, wb, zacc, 0, 0, 0);
            if (c < 18) af = *(const bf16x8*)(aprow + (c + 1)*16*NB);
            const uint w0 = (uint)f2bf(facc[0]) | ((uint)f2bf(facc[1]) << 16);
            const uint w1 = (uint)f2bf(facc[2]) | ((uint)f2bf(facc[3]) << 16);
            *(uint2*)(wp + c*32) = make_uint2(w0, w1);
        }
    }
    __syncthreads();   // F-tile complete; ppl visible to all

    if (wv == 0) {
        // ---- phase 2b: recurrence, lane = channel (no redundancy) ----
        const float4 pp = *(const float4*)(pplf + j*4);  // {goal,kfac,az,v}
        const float az = pp.z;
        const float Ac = DTF * az * az * 0.25f;
        const float Bc = DTF * az;
        const float Kc = DTF * pp.y;
        const float c0 = Ac * pp.x;
        const float OmB = 1.0f - Bc;
        float y = pp.x - pp.y;                           // y0
        float z = 0.01f;

        const char* fp = ftb + j*624;
        float* aptr = a_out + ((blockIdx.x << 6) + j)*TS;

        uint2 fc = *(const uint2*)fp;
        #pragma unroll 1
        for (int s = 0; s < 75; ++s) {
            const uint2 fn = *(const uint2*)(fp + s*8 + 8);   // prefetch (slot 75 pad ok)
            const float F0 = __uint_as_float(fc.x << 16);
            const float F1 = __uint_as_float(fc.x & 0xffff0000u);
            const float F2 = __uint_as_float(fc.y << 16);
            const float F3 = __uint_as_float(fc.y & 0xffff0000u);
            float a0, a1, a2, a3;
            {
                a0 = z * DTF;
                const float t2 = fmaf(-Ac, y, fmaf(Kc, F0, c0));
                y += a0;  z = fmaf(OmB, z, t2);
            }
            {
                a1 = z * DTF;
                const float t2 = fmaf(-Ac, y, fmaf(Kc, F1, c0));
                y += a1;  z = fmaf(OmB, z, t2);
            }
            {
                a2 = z * DTF;
                const float t2 = fmaf(-Ac, y, fmaf(Kc, F2, c0));
                y += a2;  z = fmaf(OmB, z, t2);
            }
            {
                a3 = z * DTF;
                const float t2 = fmaf(-Ac, y, fmaf(Kc, F3, c0));
                y += a3;  z = fmaf(OmB, z, t2);
            }
            *(float4*)(aptr + s*4) = make_float4(a0, a1, a2, a3);
            fc = fn;
        }
    } else {
        // ---- phase 2b': v-sweep (3 waves, linear full-line stores) ----
        float* vbase = v_out + blockIdx.x * 19200;
        #pragma unroll 1
        for (int i = tid - 64; i < 4800; i += 192) {
            const int chv = (int)((unsigned)i / 75u);
            const float vv = pplf[chv*4 + 3];
            *(float4*)(vbase + i*4) = make_float4(vv, vv, vv, vv);
        }
    }
}

extern "C" void kernel_launch(void* const* d_in, const int* in_sizes, int n_in,
                              void* d_out, int out_size, void* d_ws, size_t ws_size,
                              hipStream_t stream) {
    (void)in_sizes; (void)n_in; (void)out_size; (void)d_ws; (void)ws_size;
    const float* state  = (const float*)d_in[0];
    const float* fc1_w  = (const float*)d_in[1];
    const float* fc1_b  = (const float*)d_in[2];
    const float* fc2m_w = (const float*)d_in[3];
    const float* fc2m_b = (const float*)d_in[4];
    const float* sig_w  = (const float*)d_in[5];
    const float* sig_b  = (const float*)d_in[6];
    const float* val_w  = (const float*)d_in[7];
    const float* val_b  = (const float*)d_in[8];
    const float* dmp_c  = (const float*)d_in[9];
    const float* dmp_s2 = (const float*)d_in[10];

    float* out     = (float*)d_out;
    float* a_out   = out;
    float* sig_out = out + A_ELEMS;
    float* v_out   = out + A_ELEMS + NBATCH*2;

    k_fused<<<dim3(512), dim3(256), 0, stream>>>(state, fc1_w, fc1_b, fc2m_w, fc2m_b,
                                                 sig_w, sig_b, val_w, val_b,
                                                 dmp_c, dmp_s2,
                                                 sig_out, a_out, v_out);
}

// Round 8
// 33.305 us; speedup vs baseline: 8.7769x; 1.2622x over previous
//
#include <hip/hip_runtime.h>
#include <hip/hip_bf16.h>

#define NB 32
#define TS 300
#define NBATCH 16384
#define DTF (1.0f/300.0f)
#define A_ELEMS (NBATCH*2*TS)   /* 9,830,400 */

typedef __attribute__((ext_vector_type(8))) short bf16x8;
typedef __attribute__((ext_vector_type(4))) float f32x4;

static __device__ __forceinline__ ushort f2bf(float f) {
    union { __hip_bfloat16 h; ushort u; } cv;
    cv.h = __float2bfloat16(f);
    return cv.u;
}

// ws layout (bytes):
//   0      : wsPhi  19*64 uint4 = 19456 B  (phi A-fragments, bf16)
//   19456  : wsB    640 uint4   = 10240 B  (W2cat B-fragments, bf16)
//   29696  : wsBias 80 f32      =   320 B
//   32768  : pbuf   32768 float4 = 512 KB  ({goal,kfac,az,v} per channel)
//   557056 : wbuf16 32768*32 bf16 = 2 MB   (per-channel basis weights)

// ---------------- kernel 0: one-block prep ----------------
// t<304: phi row -> 4 A-fragment uint4s. 304..943: B-fragment pack.
// 944..1023: bias table.
__global__ __launch_bounds__(1024) void k_prep(
    const float* __restrict__ fc2m_w, const float* __restrict__ fc2m_b,
    const float* __restrict__ sig_w, const float* __restrict__ sig_b,
    const float* __restrict__ val_w, const float* __restrict__ val_b,
    const float* __restrict__ dmp_c, const float* __restrict__ dmp_s2,
    uint4* __restrict__ wsPhi, uint4* __restrict__ wsB,
    float* __restrict__ wsBias)
{
    const int t = threadIdx.x;
    if (t < 304) {
        ushort row[NB];
        if (t < TS) {
            const float x = exp2f((float)(t + 1) * log2f(1.0f - DTF));
            float ps[NB]; float s = 0.0f;
            #pragma unroll
            for (int n = 0; n < NB; ++n) {
                float d = x - dmp_c[n];
                float p = __expf(-0.5f * d * d / dmp_s2[n]);
                ps[n] = p; s += p;
            }
            const float inv = x / s;
            #pragma unroll
            for (int n = 0; n < NB; ++n) row[n] = f2bf(ps[n] * inv);
        } else {
            #pragma unroll
            for (int n = 0; n < NB; ++n) row[n] = 0;
        }
        #pragma unroll
        for (int g0 = 0; g0 < 4; ++g0) {
            union { ushort us[8]; uint4 v; } pk;
            #pragma unroll
            for (int e = 0; e < 8; ++e) pk.us[e] = row[g0*8 + e];
            wsPhi[(t >> 4)*64 + g0*16 + (t & 15)] = pk.v;
        }
    } else if (t < 944) {
        const int e = t - 304;                 // 0..639
        const int T = e >> 7, kk = (e >> 6) & 1, lane = e & 63;
        const int r = T*16 + (lane & 15);
        const int k0 = kk*32 + (lane >> 4)*8;
        union { ushort us[8]; uint4 v; } pk;
        if (r < 70) {
            const float* src = (r < 66) ? (fc2m_w + r*64 + k0)
                             : (r < 68) ? (sig_w + (r-66)*64 + k0)
                             : (val_w + (r-68)*64 + k0);
            #pragma unroll
            for (int i = 0; i < 8; ++i) pk.us[i] = f2bf(src[i]);
        } else {
            #pragma unroll
            for (int i = 0; i < 8; ++i) pk.us[i] = 0;
        }
        wsB[e] = pk.v;
    } else {
        const int r = t - 944;                 // 0..79
        wsBias[r] = (r < 66) ? fc2m_b[r] : (r < 68) ? sig_b[r-66]
                  : (r < 70) ? val_b[r-68] : 0.0f;
    }
}

// ---------------- kernel 1: MFMA heads ----------------
// 256 blocks x 4 waves; wave = 16 batches x 70 output rows (5 col-tiles).
__global__ __launch_bounds__(256) void k_head(
    const float* __restrict__ state,
    const float* __restrict__ fc1_w, const float* __restrict__ fc1_b,
    const uint4* __restrict__ wsB, const float* __restrict__ wsBias,
    float* __restrict__ sig_out, float* __restrict__ pbuf,
    ushort* __restrict__ wbuf16)
{
    __shared__ float f1[64*4];
    __shared__ float biasl[80];
    __shared__ float hlds[4*16*68];    // per-wave h, row stride 68 (17,408 B)
    __shared__ float ct[4*16*84];      // per-wave C, row stride 84 (21,504 B)

    const int tid = threadIdx.x;
    const int wv  = tid >> 6;
    const int l   = tid & 63;
    const int b16 = l & 15;            // batch-in-tile / C col group
    const int g   = l >> 4;

    if (tid < 64) {
        f1[tid*4+0] = fc1_w[tid*3+0];
        f1[tid*4+1] = fc1_w[tid*3+1];
        f1[tid*4+2] = fc1_w[tid*3+2];
        f1[tid*4+3] = fc1_b[tid];
    }
    if (tid < 80) biasl[tid] = wsBias[tid];
    __syncthreads();

    const int bbase = blockIdx.x*64 + wv*16;
    const int bglob = bbase + b16;
    const float s0 = state[bglob*3+0], s1 = state[bglob*3+1], s2 = state[bglob*3+2];

    // h: lane computes hid = g + 4i for its batch b16
    float* hrow = hlds + wv*1088 + b16*68;
    #pragma unroll
    for (int i = 0; i < 16; ++i) {
        const int hid = g + 4*i;
        const float4 fw = *(const float4*)(f1 + hid*4);
        const float pre = fmaf(fw.x, s0, fmaf(fw.y, s1, fmaf(fw.z, s2, fw.w)));
        const float e = __expf(2.0f * pre);
        hrow[hid] = (1.0f - 2.0f/(e + 1.0f)) * 0.1f;   // tanh, overflow-safe
    }

    // A-fragments (same-wave DS ordering; no barrier needed)
    bf16x8 A0, A1;
    {
        const float* hr = hlds + wv*1088 + b16*68 + g*8;
        const float4 h0 = *(const float4*)(hr),     h1 = *(const float4*)(hr + 4);
        const float4 h2 = *(const float4*)(hr + 32), h3 = *(const float4*)(hr + 36);
        union { bf16x8 v; ushort u[8]; } p0, p1;
        p0.u[0]=f2bf(h0.x); p0.u[1]=f2bf(h0.y); p0.u[2]=f2bf(h0.z); p0.u[3]=f2bf(h0.w);
        p0.u[4]=f2bf(h1.x); p0.u[5]=f2bf(h1.y); p0.u[6]=f2bf(h1.z); p0.u[7]=f2bf(h1.w);
        p1.u[0]=f2bf(h2.x); p1.u[1]=f2bf(h2.y); p1.u[2]=f2bf(h2.z); p1.u[3]=f2bf(h2.w);
        p1.u[4]=f2bf(h3.x); p1.u[5]=f2bf(h3.y); p1.u[6]=f2bf(h3.z); p1.u[7]=f2bf(h3.w);
        A0 = p0.v; A1 = p1.v;
    }

    // 5 col-tiles x (2 MFMAs) -> C rows to LDS (+bias)
    float* ctw = ct + wv*1344;
    const f32x4 zacc = {0.0f, 0.0f, 0.0f, 0.0f};
    #pragma unroll
    for (int T = 0; T < 5; ++T) {
        union { uint4 q; bf16x8 v; } B0, B1;
        B0.q = wsB[(T*2+0)*64 + l];
        B1.q = wsB[(T*2+1)*64 + l];
        f32x4 acc = __builtin_amdgcn_mfma_f32_16x16x32_bf16(A0, B0.v, zacc, 0, 0, 0);
        acc = __builtin_amdgcn_mfma_f32_16x16x32_bf16(A1, B1.v, acc, 0, 0, 0);
        const int r = T*16 + b16;
        const float bs = biasl[r];
        #pragma unroll
        for (int reg = 0; reg < 4; ++reg)
            ctw[(g*4 + reg)*84 + r] = acc[reg] + bs;
    }

    // epilogue: w-pack (lanes 0..31), 16 batches
    uint* wout = (uint*)wbuf16;
    #pragma unroll 1
    for (int b = 0; b < 16; ++b) {
        if (l < 32) {
            const float2 wp = *(const float2*)(ctw + b*84 + 2 + 2*l);
            wout[(bbase + b)*32 + l] = (uint)f2bf(wp.x) | ((uint)f2bf(wp.y) << 16);
        }
    }
    // specials (batch-parallel across lanes)
    if (l < 16) {
        const float* cb = ctw + l*84;
        const float goal = cb[0];
        const float az = fminf(fmaxf(cb[65], 0.5f), 30.0f);
        const float y0 = state[(bbase + l)*3 + 0];
        *(float4*)(pbuf + ((bbase + l)*2 + 0)*4) = make_float4(goal, goal - y0, az, cb[68]);
    } else if (l < 32) {
        const int b = l - 16;
        const float* cb = ctw + b*84;
        const float goal = cb[1];
        const float az = fminf(fmaxf(cb[65], 0.5f), 30.0f);
        const float y0 = state[(bbase + b)*3 + 1];
        *(float4*)(pbuf + ((bbase + b)*2 + 1)*4) = make_float4(goal, goal - y0, az, cb[69]);
    } else if (l < 48) {
        const int b = l - 32;
        const float* cb = ctw + b*84;
        const float sg0 = 1.0f / (1.0f + __expf(-cb[66])) + 0.001f;
        const float sg1 = 1.0f / (1.0f + __expf(-cb[67])) + 0.001f;
        *(float2*)(sig_out + (bbase + b)*2) = make_float2(sg0, sg1);
    }
}

// ---------------- kernel 2: rollout (R4 structure, global phi/w) ----------------
__global__ __launch_bounds__(256) void k_roll(
    const uint4* __restrict__ wsPhi, const float* __restrict__ pbuf,
    const ushort* __restrict__ wbuf16, float* __restrict__ a_out,
    float* __restrict__ v_out)
{
    __shared__ float4 xt[4][16][5];
    const int tid = threadIdx.x;
    const int wv = tid >> 6;
    const int j  = tid & 63;
    const int ch = j & 15;
    const int g  = j >> 4;
    const int m  = (blockIdx.x << 6) + (wv << 4) + ch;

    const float4 pp = *(const float4*)(pbuf + m*4);   // {goal, kfac, az, v}
    const float az = pp.z;
    const float Ac = DTF * az * az * 0.25f;
    const float Kc = DTF * pp.y;
    const float c0 = Ac * pp.x;
    const float OmB = 1.0f - DTF * az;
    float y = pp.x - pp.y;                            // y0
    float z = 0.01f;

    const bf16x8 wb = *(const bf16x8*)(wbuf16 + m*NB + g*8);
    const bf16x8* ap = (const bf16x8*)wsPhi;
    bf16x8 af = ap[j];

    const int mloc = j >> 2;
    const int m_st = (blockIdx.x << 6) + (wv << 4) + mloc;
    float* aptr = a_out + m_st*TS + (j & 3)*4;
    float* vptr = v_out + m_st*TS + (j & 3)*4;
    const bool tail_ok = (j & 3) < 3;
    float4 vsp;
    {
        const float fv = pbuf[((blockIdx.x << 6) + (wv << 4) + mloc)*4 + 3];
        vsp = make_float4(fv, fv, fv, fv);
    }

    const f32x4 zacc = {0.0f, 0.0f, 0.0f, 0.0f};

    for (int c = 0; c < 19; ++c) {
        f32x4 facc = __builtin_amdgcn_mfma_f32_16x16x32_bf16(af, wb, zacc, 0, 0, 0);
        if (c < 18) af = ap[(c + 1)*64 + j];

        // all-gather F[0..15] across the 4 g-groups (channel-preserving)
        float F[16];
        #pragma unroll
        for (int q = 0; q < 4; ++q) {
            float a = facc[q], b = facc[q];
            asm volatile("v_permlane16_swap_b32 %0, %1" : "+v"(a), "+v"(b));
            float a2 = a, b2 = b;
            asm volatile("v_permlane32_swap_b32 %0, %1" : "+v"(a), "+v"(a2));
            asm volatile("v_permlane32_swap_b32 %0, %1" : "+v"(b), "+v"(b2));
            F[0*4+q] = a; F[1*4+q] = b; F[2*4+q] = a2; F[3*4+q] = b2;
        }

        float avq[4] = {0.f, 0.f, 0.f, 0.f};
        #pragma unroll
        for (int i = 0; i < 16; ++i) {
            const float aval = z * DTF;
            if (g == (i >> 2)) avq[i & 3] = aval;
            float t2 = fmaf(Kc, F[i], c0);
            t2 = fmaf(-Ac, y, t2);
            z = fmaf(OmB, z, t2);
            y += aval;
        }

        xt[wv][ch][g] = make_float4(avq[0], avq[1], avq[2], avq[3]);
        if (c < 18 || tail_ok) {
            const float4 s4 = xt[wv][mloc][j & 3];
            *(float4*)aptr = s4;
            *(float4*)vptr = vsp;
        }
        aptr += 16; vptr += 16;
    }
}

extern "C" void kernel_launch(void* const* d_in, const int* in_sizes, int n_in,
                              void* d_out, int out_size, void* d_ws, size_t ws_size,
                              hipStream_t stream) {
    (void)in_sizes; (void)n_in; (void)out_size; (void)ws_size;
    const float* state  = (const float*)d_in[0];
    const float* fc1_w  = (const float*)d_in[1];
    const float* fc1_b  = (const float*)d_in[2];
    const float* fc2m_w = (const float*)d_in[3];
    const float* fc2m_b = (const float*)d_in[4];
    const float* sig_w  = (const float*)d_in[5];
    const float* sig_b  = (const float*)d_in[6];
    const float* val_w  = (const float*)d_in[7];
    const float* val_b  = (const float*)d_in[8];
    const float* dmp_c  = (const float*)d_in[9];
    const float* dmp_s2 = (const float*)d_in[10];

    float* out     = (float*)d_out;
    float* a_out   = out;
    float* sig_out = out + A_ELEMS;
    float* v_out   = out + A_ELEMS + NBATCH*2;

    char* ws = (char*)d_ws;
    uint4*  wsPhi  = (uint4*)ws;
    uint4*  wsB    = (uint4*)(ws + 19456);
    float*  wsBias = (float*)(ws + 29696);
    float*  pbuf   = (float*)(ws + 32768);
    ushort* wbuf16 = (ushort*)(ws + 557056);

    k_prep<<<dim3(1), dim3(1024), 0, stream>>>(fc2m_w, fc2m_b, sig_w, sig_b,
                                               val_w, val_b, dmp_c, dmp_s2,
                                               wsPhi, wsB, wsBias);
    k_head<<<dim3(256), dim3(256), 0, stream>>>(state, fc1_w, fc1_b, wsB, wsBias,
                                                sig_out, pbuf, wbuf16);
    k_roll<<<dim3(512), dim3(256), 0, stream>>>(wsPhi, pbuf, wbuf16, a_out, v_out);
}

// Round 9
// 30.634 us; speedup vs baseline: 9.5422x; 1.0872x over previous
//
#include <hip/hip_runtime.h>
#include <hip/hip_bf16.h>

#define NB 32
#define TS 300
#define NBATCH 16384
#define DTF (1.0f/300.0f)
#define A_ELEMS (NBATCH*2*TS)   /* 9,830,400 */

typedef __attribute__((ext_vector_type(8))) short bf16x8;
typedef __attribute__((ext_vector_type(4))) float f32x4;

static __device__ __forceinline__ ushort f2bf(float f) {
    union { __hip_bfloat16 h; ushort u; } cv;
    cv.h = __float2bfloat16(f);
    return cv.u;
}

// ws layout (bytes):
//   0      : wsPhi  19*64 uint4 = 19456 B   (phi A-fragments, bf16)
//   32768  : pbuf   32768 float4 = 512 KB   ({goal, az, y0, v} per channel)
//   557056 : wbuf16 32768*32 bf16 = 2 MB    (prescaled basis weights, = DTF*kfac*w)

// ---------------- kernel 1: MFMA heads (blocks 0..255) + phi (block 256) ----------------
__global__ __launch_bounds__(256) void k_head(
    const float* __restrict__ state,
    const float* __restrict__ fc1_w, const float* __restrict__ fc1_b,
    const float* __restrict__ fc2m_w, const float* __restrict__ fc2m_b,
    const float* __restrict__ sig_w, const float* __restrict__ sig_b,
    const float* __restrict__ val_w, const float* __restrict__ val_b,
    const float* __restrict__ dmp_c, const float* __restrict__ dmp_s2,
    float* __restrict__ sig_out, float* __restrict__ pbuf,
    ushort* __restrict__ wbuf16, uint4* __restrict__ wsPhi)
{
    const int tid = threadIdx.x;
    if (blockIdx.x == 256) {
        // phi A-fragment table -> ws (bf16), layout [chunk][g*16+ch]
        const float l2 = log2f(1.0f - DTF);
        for (int t = tid; t < 304; t += 256) {
            ushort row[NB];
            if (t < TS) {
                const float x = exp2f((float)(t + 1) * l2);
                float ps[NB]; float s = 0.0f;
                #pragma unroll
                for (int n = 0; n < NB; ++n) {
                    float d = x - dmp_c[n];
                    float p = __expf(-0.5f * d * d / dmp_s2[n]);
                    ps[n] = p; s += p;
                }
                const float inv = x / s;
                #pragma unroll
                for (int n = 0; n < NB; ++n) row[n] = f2bf(ps[n] * inv);
            } else {
                #pragma unroll
                for (int n = 0; n < NB; ++n) row[n] = 0;
            }
            #pragma unroll
            for (int g0 = 0; g0 < 4; ++g0) {
                union { ushort us[8]; uint4 v; } pk;
                #pragma unroll
                for (int e = 0; e < 8; ++e) pk.us[e] = row[g0*8 + e];
                wsPhi[(t >> 4)*64 + g0*16 + (t & 15)] = pk.v;
            }
        }
        return;
    }

    __shared__ uint4 bfr[640];          // B-fragments (10,240 B)
    __shared__ float f1s[64*4];
    __shared__ float biasl[80];
    __shared__ float hlds[4*16*68];     // per-wave h (17,408 B)
    __shared__ float ct[4*16*84];       // per-wave C [batch][row84] (21,504 B)
    __shared__ float scl[4][16][2];     // per-wave channel scales

    const int wv  = tid >> 6;
    const int l   = tid & 63;
    const int b16 = l & 15;
    const int g   = l >> 4;

    // B-fragment staging (shared across waves)
    for (int e = tid; e < 640; e += 256) {
        const int T = e >> 7, kk = (e >> 6) & 1, lane = e & 63;
        const int r = T*16 + (lane & 15);
        const int k0 = kk*32 + (lane >> 4)*8;
        union { ushort us[8]; uint4 v; } pk;
        if (r < 70) {
            const float* src = (r < 66) ? (fc2m_w + r*64 + k0)
                             : (r < 68) ? (sig_w + (r-66)*64 + k0)
                             : (val_w + (r-68)*64 + k0);
            #pragma unroll
            for (int i = 0; i < 8; ++i) pk.us[i] = f2bf(src[i]);
        } else {
            #pragma unroll
            for (int i = 0; i < 8; ++i) pk.us[i] = 0;
        }
        bfr[e] = pk.v;
    }
    if (tid < 64) {
        f1s[tid*4+0] = fc1_w[tid*3+0];
        f1s[tid*4+1] = fc1_w[tid*3+1];
        f1s[tid*4+2] = fc1_w[tid*3+2];
        f1s[tid*4+3] = fc1_b[tid];
    }
    if (tid < 80) biasl[tid] = (tid < 66) ? fc2m_b[tid] : (tid < 68) ? sig_b[tid-66]
                             : (tid < 70) ? val_b[tid-68] : 0.0f;
    __syncthreads();

    const int bbase = blockIdx.x*64 + wv*16;
    const int bglob = bbase + b16;
    const float s0 = state[bglob*3+0], s1 = state[bglob*3+1], s2 = state[bglob*3+2];

    // h: lane computes hid = g + 4i for its batch b16
    float* hrow = hlds + wv*1088 + b16*68;
    #pragma unroll
    for (int i = 0; i < 16; ++i) {
        const int hid = g + 4*i;
        const float4 fw = *(const float4*)(f1s + hid*4);
        const float pre = fmaf(fw.x, s0, fmaf(fw.y, s1, fmaf(fw.z, s2, fw.w)));
        const float e = __expf(2.0f * pre);
        hrow[hid] = (1.0f - 2.0f/(e + 1.0f)) * 0.1f;   // tanh, overflow-safe
    }

    // A-fragments (same-wave DS ordering; no barrier needed)
    bf16x8 A0, A1;
    {
        const float* hr = hlds + wv*1088 + b16*68 + g*8;
        const float4 h0 = *(const float4*)(hr),      h1 = *(const float4*)(hr + 4);
        const float4 h2 = *(const float4*)(hr + 32), h3 = *(const float4*)(hr + 36);
        union { bf16x8 v; ushort u[8]; } p0, p1;
        p0.u[0]=f2bf(h0.x); p0.u[1]=f2bf(h0.y); p0.u[2]=f2bf(h0.z); p0.u[3]=f2bf(h0.w);
        p0.u[4]=f2bf(h1.x); p0.u[5]=f2bf(h1.y); p0.u[6]=f2bf(h1.z); p0.u[7]=f2bf(h1.w);
        p1.u[0]=f2bf(h2.x); p1.u[1]=f2bf(h2.y); p1.u[2]=f2bf(h2.z); p1.u[3]=f2bf(h2.w);
        p1.u[4]=f2bf(h3.x); p1.u[5]=f2bf(h3.y); p1.u[6]=f2bf(h3.z); p1.u[7]=f2bf(h3.w);
        A0 = p0.v; A1 = p1.v;
    }

    // 5 col-tiles x 2 MFMAs -> C rows to LDS (+bias)
    float* ctw = ct + wv*1344;
    const f32x4 zacc = {0.0f, 0.0f, 0.0f, 0.0f};
    #pragma unroll
    for (int T = 0; T < 5; ++T) {
        union { uint4 q; bf16x8 v; } B0, B1;
        B0.q = bfr[(T*2+0)*64 + l];
        B1.q = bfr[(T*2+1)*64 + l];
        f32x4 acc = __builtin_amdgcn_mfma_f32_16x16x32_bf16(A0, B0.v, zacc, 0, 0, 0);
        acc = __builtin_amdgcn_mfma_f32_16x16x32_bf16(A1, B1.v, acc, 0, 0, 0);
        const int r = T*16 + b16;
        const float bs = biasl[r];
        #pragma unroll
        for (int reg = 0; reg < 4; ++reg)
            ctw[(g*4 + reg)*84 + r] = acc[reg] + bs;
    }

    // channel scales: DTF * (goal - y0), per (batch, dim)
    if (l < 32) {
        const int b = l & 15, d = l >> 4;
        const float goal = ctw[b*84 + d];
        const float y0 = state[(bbase + b)*3 + d];
        scl[wv][b][d] = DTF * (goal - y0);
    }

    // w-pack: prescaled bf16 (lanes 0..31 cover 64 w-cols = both dims)
    uint* wout = (uint*)wbuf16;
    #pragma unroll 1
    for (int b = 0; b < 16; ++b) {
        if (l < 32) {
            const float2 wp = *(const float2*)(ctw + b*84 + 2 + 2*l);
            const float sc = scl[wv][b][l >> 4];
            wout[(bbase + b)*32 + l] =
                (uint)f2bf(wp.x * sc) | ((uint)f2bf(wp.y * sc) << 16);
        }
    }
    // specials
    if (l < 16) {
        const float* cb = ctw + l*84;
        const float az = fminf(fmaxf(cb[65], 0.5f), 30.0f);
        const float y0 = state[(bbase + l)*3 + 0];
        *(float4*)(pbuf + ((bbase + l)*2 + 0)*4) = make_float4(cb[0], az, y0, cb[68]);
    } else if (l < 32) {
        const int b = l - 16;
        const float* cb = ctw + b*84;
        const float az = fminf(fmaxf(cb[65], 0.5f), 30.0f);
        const float y0 = state[(bbase + b)*3 + 1];
        *(float4*)(pbuf + ((bbase + b)*2 + 1)*4) = make_float4(cb[1], az, y0, cb[69]);
    } else if (l < 48) {
        const int b = l - 32;
        const float* cb = ctw + b*84;
        const float sg0 = 1.0f / (1.0f + __expf(-cb[66])) + 0.001f;
        const float sg1 = 1.0f / (1.0f + __expf(-cb[67])) + 0.001f;
        *(float2*)(sig_out + (bbase + b)*2) = make_float2(sg0, sg1);
    }
}

// ---------------- kernel 2: rollout ----------------
// F' = c0 + Kc*F comes straight from MFMA (prescaled wb, C-operand = c0).
// Per step: 4 fma + 1 select. z stored raw; DTF applied at store.
// xt double-buffered: chunk c stores chunk c-1's transpose (no lgkm stall);
// v-store issued at chunk top (dependency-free, drains under compute).
__global__ __launch_bounds__(256) void k_roll(
    const uint4* __restrict__ wsPhi, const float* __restrict__ pbuf,
    const ushort* __restrict__ wbuf16, float* __restrict__ a_out,
    float* __restrict__ v_out)
{
    __shared__ float4 xt[2][4][16][5];
    const int tid = threadIdx.x;
    const int wv = tid >> 6;
    const int j  = tid & 63;
    const int ch = j & 15;
    const int g  = j >> 4;
    const int m  = (blockIdx.x << 6) + (wv << 4) + ch;

    const float4 pp = *(const float4*)(pbuf + m*4);   // {goal, az, y0, v}
    const float az = pp.y;
    const float Ac = (DTF * 0.25f) * az * az;
    const float OmB = fmaf(-DTF, az, 1.0f);
    const float c0 = Ac * pp.x;
    float y = pp.z;                                   // y0
    float z = 0.01f;
    const f32x4 cvec = {c0, c0, c0, c0};

    const bf16x8 wb = *(const bf16x8*)(wbuf16 + m*NB + g*8);   // prescaled
    const bf16x8* ap = (const bf16x8*)wsPhi;
    bf16x8 af = ap[j];

    const int mloc = j >> 2;
    const int m_st = (blockIdx.x << 6) + (wv << 4) + mloc;
    float* aptr = a_out + m_st*TS + (j & 3)*4;
    float* vptr = v_out + m_st*TS + (j & 3)*4;
    const bool tail_ok = (j & 3) < 3;
    float4 vsp;
    {
        const float fv = pbuf[m_st*4 + 3];
        vsp = make_float4(fv, fv, fv, fv);
    }

    for (int c = 0; c < 19; ++c) {
        if (c < 18 || tail_ok) { *(float4*)vptr = vsp; }
        vptr += 16;

        f32x4 facc = __builtin_amdgcn_mfma_f32_16x16x32_bf16(af, wb, cvec, 0, 0, 0);
        if (c < 18) af = ap[(c + 1)*64 + j];

        // all-gather F'[0..15] across the 4 g-groups (channel-preserving)
        float F[16];
        #pragma unroll
        for (int q = 0; q < 4; ++q) {
            float a = facc[q], b = facc[q];
            asm volatile("v_permlane16_swap_b32 %0, %1" : "+v"(a), "+v"(b));
            float a2 = a, b2 = b;
            asm volatile("v_permlane32_swap_b32 %0, %1" : "+v"(a), "+v"(a2));
            asm volatile("v_permlane32_swap_b32 %0, %1" : "+v"(b), "+v"(b2));
            F[0*4+q] = a; F[1*4+q] = b; F[2*4+q] = a2; F[3*4+q] = b2;
        }

        float avq[4] = {0.f, 0.f, 0.f, 0.f};
        #pragma unroll
        for (int i = 0; i < 16; ++i) {
            const float t2 = fmaf(-Ac, y, F[i]);       // F already = c0 + Kc*F
            if (g == (i >> 2)) avq[i & 3] = z;          // raw z; DTF at store
            y = fmaf(DTF, z, y);
            z = fmaf(OmB, z, t2);
        }

        if (c > 0) {
            const float4 xs = xt[(c - 1) & 1][wv][mloc][j & 3];
            *(float4*)aptr = make_float4(xs.x*DTF, xs.y*DTF, xs.z*DTF, xs.w*DTF);
            aptr += 16;
        }
        xt[c & 1][wv][ch][g] = make_float4(avq[0], avq[1], avq[2], avq[3]);
    }
    // epilogue: chunk 18 (t 288..299; quad 3 masked)
    if (tail_ok) {
        const float4 xs = xt[0][wv][mloc][j & 3];      // 18&1 == 0
        *(float4*)aptr = make_float4(xs.x*DTF, xs.y*DTF, xs.z*DTF, xs.w*DTF);
    }
}

extern "C" void kernel_launch(void* const* d_in, const int* in_sizes, int n_in,
                              void* d_out, int out_size, void* d_ws, size_t ws_size,
                              hipStream_t stream) {
    (void)in_sizes; (void)n_in; (void)out_size; (void)ws_size;
    const float* state  = (const float*)d_in[0];
    const float* fc1_w  = (const float*)d_in[1];
    const float* fc1_b  = (const float*)d_in[2];
    const float* fc2m_w = (const float*)d_in[3];
    const float* fc2m_b = (const float*)d_in[4];
    const float* sig_w  = (const float*)d_in[5];
    const float* sig_b  = (const float*)d_in[6];
    const float* val_w  = (const float*)d_in[7];
    const float* val_b  = (const float*)d_in[8];
    const float* dmp_c  = (const float*)d_in[9];
    const float* dmp_s2 = (const float*)d_in[10];

    float* out     = (float*)d_out;
    float* a_out   = out;
    float* sig_out = out + A_ELEMS;
    float* v_out   = out + A_ELEMS + NBATCH*2;

    char* ws = (char*)d_ws;
    uint4*  wsPhi  = (uint4*)ws;
    float*  pbuf   = (float*)(ws + 32768);
    ushort* wbuf16 = (ushort*)(ws + 557056);

    k_head<<<dim3(257), dim3(256), 0, stream>>>(state, fc1_w, fc1_b, fc2m_w, fc2m_b,
                                                sig_w, sig_b, val_w, val_b,
                                                dmp_c, dmp_s2,
                                                sig_out, pbuf, wbuf16, wsPhi);
    k_roll<<<dim3(512), dim3(256), 0, stream>>>(wsPhi, pbuf, wbuf16, a_out, v_out);
}

// Round 12
// 30.029 us; speedup vs baseline: 9.7345x; 1.0201x over previous
//
#include <hip/hip_runtime.h>
#include <hip/hip_bf16.h>

#define NB 32
#define TS 300
#define NBATCH 16384
#define DTF (1.0f/300.0f)
#define A_ELEMS (NBATCH*2*TS)   /* 9,830,400 */

typedef __attribute__((ext_vector_type(8))) short bf16x8;
typedef __attribute__((ext_vector_type(4))) float f32x4;

static __device__ __forceinline__ ushort f2bf(float f) {
    union { __hip_bfloat16 h; ushort u; } cv;
    cv.h = __float2bfloat16(f);
    return cv.u;
}

// ws layout (bytes):
//   0      : wsPhi  19*64 uint4 = 19456 B   (phi A-fragments, bf16)
//   32768  : pbuf   32768 float4 = 512 KB   ({goal, az, y0, v} per channel)
//   557056 : wbuf16 32768*32 bf16 = 2 MB    (prescaled basis weights = DTF*kfac*w)

// ---------------- kernel 1: MFMA heads (blocks 0..255) + phi (block 256) ----------------
// (verbatim R9 — passed twice)
__global__ __launch_bounds__(256) void k_head(
    const float* __restrict__ state,
    const float* __restrict__ fc1_w, const float* __restrict__ fc1_b,
    const float* __restrict__ fc2m_w, const float* __restrict__ fc2m_b,
    const float* __restrict__ sig_w, const float* __restrict__ sig_b,
    const float* __restrict__ val_w, const float* __restrict__ val_b,
    const float* __restrict__ dmp_c, const float* __restrict__ dmp_s2,
    float* __restrict__ sig_out, float* __restrict__ pbuf,
    ushort* __restrict__ wbuf16, uint4* __restrict__ wsPhi)
{
    const int tid = threadIdx.x;
    if (blockIdx.x == 256) {
        // phi A-fragment table -> ws (bf16), layout [chunk][g*16+ch]
        const float l2 = log2f(1.0f - DTF);
        for (int t = tid; t < 304; t += 256) {
            ushort row[NB];
            if (t < TS) {
                const float x = exp2f((float)(t + 1) * l2);
                float ps[NB]; float s = 0.0f;
                #pragma unroll
                for (int n = 0; n < NB; ++n) {
                    float d = x - dmp_c[n];
                    float p = __expf(-0.5f * d * d / dmp_s2[n]);
                    ps[n] = p; s += p;
                }
                const float inv = x / s;
                #pragma unroll
                for (int n = 0; n < NB; ++n) row[n] = f2bf(ps[n] * inv);
            } else {
                #pragma unroll
                for (int n = 0; n < NB; ++n) row[n] = 0;
            }
            #pragma unroll
            for (int g0 = 0; g0 < 4; ++g0) {
                union { ushort us[8]; uint4 v; } pk;
                #pragma unroll
                for (int e = 0; e < 8; ++e) pk.us[e] = row[g0*8 + e];
                wsPhi[(t >> 4)*64 + g0*16 + (t & 15)] = pk.v;
            }
        }
        return;
    }

    __shared__ uint4 bfr[640];          // B-fragments (10,240 B)
    __shared__ float f1s[64*4];
    __shared__ float biasl[80];
    __shared__ float hlds[4*16*68];     // per-wave h (17,408 B)
    __shared__ float ct[4*16*84];       // per-wave C [batch][row84] (21,504 B)
    __shared__ float scl[4][16][2];     // per-wave channel scales

    const int wv  = tid >> 6;
    const int l   = tid & 63;
    const int b16 = l & 15;
    const int g   = l >> 4;

    // B-fragment staging (shared across waves)
    for (int e = tid; e < 640; e += 256) {
        const int T = e >> 7, kk = (e >> 6) & 1, lane = e & 63;
        const int r = T*16 + (lane & 15);
        const int k0 = kk*32 + (lane >> 4)*8;
        union { ushort us[8]; uint4 v; } pk;
        if (r < 70) {
            const float* src = (r < 66) ? (fc2m_w + r*64 + k0)
                             : (r < 68) ? (sig_w + (r-66)*64 + k0)
                             : (val_w + (r-68)*64 + k0);
            #pragma unroll
            for (int i = 0; i < 8; ++i) pk.us[i] = f2bf(src[i]);
        } else {
            #pragma unroll
            for (int i = 0; i < 8; ++i) pk.us[i] = 0;
        }
        bfr[e] = pk.v;
    }
    if (tid < 64) {
        f1s[tid*4+0] = fc1_w[tid*3+0];
        f1s[tid*4+1] = fc1_w[tid*3+1];
        f1s[tid*4+2] = fc1_w[tid*3+2];
        f1s[tid*4+3] = fc1_b[tid];
    }
    if (tid < 80) biasl[tid] = (tid < 66) ? fc2m_b[tid] : (tid < 68) ? sig_b[tid-66]
                             : (tid < 70) ? val_b[tid-68] : 0.0f;
    __syncthreads();

    const int bbase = blockIdx.x*64 + wv*16;
    const int bglob = bbase + b16;
    const float s0 = state[bglob*3+0], s1 = state[bglob*3+1], s2 = state[bglob*3+2];

    // h: lane computes hid = g + 4i for its batch b16
    float* hrow = hlds + wv*1088 + b16*68;
    #pragma unroll
    for (int i = 0; i < 16; ++i) {
        const int hid = g + 4*i;
        const float4 fw = *(const float4*)(f1s + hid*4);
        const float pre = fmaf(fw.x, s0, fmaf(fw.y, s1, fmaf(fw.z, s2, fw.w)));
        const float e = __expf(2.0f * pre);
        hrow[hid] = (1.0f - 2.0f/(e + 1.0f)) * 0.1f;   // tanh, overflow-safe
    }

    // A-fragments (same-wave DS ordering; no barrier needed)
    bf16x8 A0, A1;
    {
        const float* hr = hlds + wv*1088 + b16*68 + g*8;
        const float4 h0 = *(const float4*)(hr),      h1 = *(const float4*)(hr + 4);
        const float4 h2 = *(const float4*)(hr + 32), h3 = *(const float4*)(hr + 36);
        union { bf16x8 v; ushort u[8]; } p0, p1;
        p0.u[0]=f2bf(h0.x); p0.u[1]=f2bf(h0.y); p0.u[2]=f2bf(h0.z); p0.u[3]=f2bf(h0.w);
        p0.u[4]=f2bf(h1.x); p0.u[5]=f2bf(h1.y); p0.u[6]=f2bf(h1.z); p0.u[7]=f2bf(h1.w);
        p1.u[0]=f2bf(h2.x); p1.u[1]=f2bf(h2.y); p1.u[2]=f2bf(h2.z); p1.u[3]=f2bf(h2.w);
        p1.u[4]=f2bf(h3.x); p1.u[5]=f2bf(h3.y); p1.u[6]=f2bf(h3.z); p1.u[7]=f2bf(h3.w);
        A0 = p0.v; A1 = p1.v;
    }

    // 5 col-tiles x 2 MFMAs -> C rows to LDS (+bias)
    float* ctw = ct + wv*1344;
    const f32x4 zacc = {0.0f, 0.0f, 0.0f, 0.0f};
    #pragma unroll
    for (int T = 0; T < 5; ++T) {
        union { uint4 q; bf16x8 v; } B0, B1;
        B0.q = bfr[(T*2+0)*64 + l];
        B1.q = bfr[(T*2+1)*64 + l];
        f32x4 acc = __builtin_amdgcn_mfma_f32_16x16x32_bf16(A0, B0.v, zacc, 0, 0, 0);
        acc = __builtin_amdgcn_mfma_f32_16x16x32_bf16(A1, B1.v, acc, 0, 0, 0);
        const int r = T*16 + b16;
        const float bs = biasl[r];
        #pragma unroll
        for (int reg = 0; reg < 4; ++reg)
            ctw[(g*4 + reg)*84 + r] = acc[reg] + bs;
    }

    // channel scales: DTF * (goal - y0), per (batch, dim)
    if (l < 32) {
        const int b = l & 15, d = l >> 4;
        const float goal = ctw[b*84 + d];
        const float y0 = state[(bbase + b)*3 + d];
        scl[wv][b][d] = DTF * (goal - y0);
    }

    // w-pack: prescaled bf16 (lanes 0..31 cover 64 w-cols = both dims)
    uint* wout = (uint*)wbuf16;
    #pragma unroll 1
    for (int b = 0; b < 16; ++b) {
        if (l < 32) {
            const float2 wp = *(const float2*)(ctw + b*84 + 2 + 2*l);
            const float sc = scl[wv][b][l >> 4];
            wout[(bbase + b)*32 + l] =
                (uint)f2bf(wp.x * sc) | ((uint)f2bf(wp.y * sc) << 16);
        }
    }
    // specials
    if (l < 16) {
        const float* cb = ctw + l*84;
        const float az = fminf(fmaxf(cb[65], 0.5f), 30.0f);
        const float y0 = state[(bbase + l)*3 + 0];
        *(float4*)(pbuf + ((bbase + l)*2 + 0)*4) = make_float4(cb[0], az, y0, cb[68]);
    } else if (l < 32) {
        const int b = l - 16;
        const float* cb = ctw + b*84;
        const float az = fminf(fmaxf(cb[65], 0.5f), 30.0f);
        const float y0 = state[(bbase + b)*3 + 1];
        *(float4*)(pbuf + ((bbase + b)*2 + 1)*4) = make_float4(cb[1], az, y0, cb[69]);
    } else if (l < 48) {
        const int b = l - 32;
        const float* cb = ctw + b*84;
        const float sg0 = 1.0f / (1.0f + __expf(-cb[66])) + 0.001f;
        const float sg1 = 1.0f / (1.0f + __expf(-cb[67])) + 0.001f;
        *(float2*)(sig_out + (bbase + b)*2) = make_float2(sg0, sg1);
    }
}

// ---------------- kernel 2: rollout (LDS-free, direct stores) ----------------
// p1==p2 (R6 probes) proved scattered-quad stores match linear BW, so the
// xt LDS transpose was pure overhead. Each lane stores its OWN channel's
// own time-quad: a_out/v_out + m*300 + c*16 + g*4 (16B aligned).
// Only masked store: c==18 && g==3 (t = 300..303 out of range).
__global__ __launch_bounds__(256) void k_roll(
    const uint4* __restrict__ wsPhi, const float* __restrict__ pbuf,
    const ushort* __restrict__ wbuf16, float* __restrict__ a_out,
    float* __restrict__ v_out)
{
    const int tid = threadIdx.x;
    const int wv = tid >> 6;
    const int j  = tid & 63;
    const int ch = j & 15;
    const int g  = j >> 4;
    const int m  = (blockIdx.x << 6) + (wv << 4) + ch;

    const float4 pp = *(const float4*)(pbuf + m*4);   // {goal, az, y0, v}
    const float az = pp.y;
    const float Ac = (DTF * 0.25f) * az * az;
    const float OmB = fmaf(-DTF, az, 1.0f);
    const float c0 = Ac * pp.x;
    float y = pp.z;                                   // y0
    float z = 0.01f;
    const f32x4 cvec = {c0, c0, c0, c0};

    const bf16x8 wb = *(const bf16x8*)(wbuf16 + m*NB + g*8);   // prescaled
    const bf16x8* ap = (const bf16x8*)wsPhi;
    bf16x8 af = ap[j];

    float* aptr = a_out + m*TS + (g << 2);
    float* vptr = v_out + m*TS + (g << 2);
    const float4 vsp = make_float4(pp.w, pp.w, pp.w, pp.w);

    for (int c = 0; c < 19; ++c) {
        const bool st = (c < 18) | (g < 3);
        if (st) { *(float4*)vptr = vsp; }             // dependency-free, drains under compute
        vptr += 16;

        f32x4 facc = __builtin_amdgcn_mfma_f32_16x16x32_bf16(af, wb, cvec, 0, 0, 0);
        if (c < 18) af = ap[(c + 1)*64 + j];

        // all-gather F'[0..15] across the 4 g-groups (channel-preserving)
        float F[16];
        #pragma unroll
        for (int q = 0; q < 4; ++q) {
            float a = facc[q], b = facc[q];
            asm volatile("v_permlane16_swap_b32 %0, %1" : "+v"(a), "+v"(b));
            float a2 = a, b2 = b;
            asm volatile("v_permlane32_swap_b32 %0, %1" : "+v"(a), "+v"(a2));
            asm volatile("v_permlane32_swap_b32 %0, %1" : "+v"(b), "+v"(b2));
            F[0*4+q] = a; F[1*4+q] = b; F[2*4+q] = a2; F[3*4+q] = b2;
        }

        float avq[4];
        #pragma unroll
        for (int i = 0; i < 16; ++i) {
            const float t2 = fmaf(-Ac, y, F[i]);       // F already = c0 + Kc*F
            if (g == (i >> 2)) avq[i & 3] = z;         // raw z; DTF at store
            y = fmaf(DTF, z, y);
            z = fmaf(OmB, z, t2);
        }

        if (st) {
            *(float4*)aptr = make_float4(avq[0]*DTF, avq[1]*DTF, avq[2]*DTF, avq[3]*DTF);
        }
        aptr += 16;
    }
}

extern "C" void kernel_launch(void* const* d_in, const int* in_sizes, int n_in,
                              void* d_out, int out_size, void* d_ws, size_t ws_size,
                              hipStream_t stream) {
    (void)in_sizes; (void)n_in; (void)out_size; (void)ws_size;
    const float* state  = (const float*)d_in[0];
    const float* fc1_w  = (const float*)d_in[1];
    const float* fc1_b  = (const float*)d_in[2];
    const float* fc2m_w = (const float*)d_in[3];
    const float* fc2m_b = (const float*)d_in[4];
    const float* sig_w  = (const float*)d_in[5];
    const float* sig_b  = (const float*)d_in[6];
    const float* val_w  = (const float*)d_in[7];
    const float* val_b  = (const float*)d_in[8];
    const float* dmp_c  = (const float*)d_in[9];
    const float* dmp_s2 = (const float*)d_in[10];

    float* out     = (float*)d_out;
    float* a_out   = out;
    float* sig_out = out + A_ELEMS;
    float* v_out   = out + A_ELEMS + NBATCH*2;

    char* ws = (char*)d_ws;
    uint4*  wsPhi  = (uint4*)ws;
    float*  pbuf   = (float*)(ws + 32768);
    ushort* wbuf16 = (ushort*)(ws + 557056);

    k_head<<<dim3(257), dim3(256), 0, stream>>>(state, fc1_w, fc1_b, fc2m_w, fc2m_b,
                                                sig_w, sig_b, val_w, val_b,
                                                dmp_c, dmp_s2,
                                                sig_out, pbuf, wbuf16, wsPhi);
    k_roll<<<dim3(512), dim3(256), 0, stream>>>(wsPhi, pbuf, wbuf16, a_out, v_out);
}